// Round 3
// baseline (90.063 us; speedup 1.0000x reference)
//
#include <hip/hip_runtime.h>
#include <hip/hip_bf16.h>

#define D 128
#define MARGIN 0.5f
#define NSPLIT 16      // j-splits; block j-window = 8192/16 = 512 cols
#define JSPAN 512      // n / NSPLIT (n = 8192 fixed by harness)

typedef __attribute__((ext_vector_type(8))) short bf16x8;
typedef __attribute__((ext_vector_type(4))) float f32x4;

// ---------------- prep: bf16 convert + sq + init ----------------
__global__ void prep_kernel(const float* __restrict__ x,
                            float* __restrict__ sq,
                            unsigned* __restrict__ ap,
                            unsigned* __restrict__ an,
                            __hip_bfloat16* __restrict__ xb,
                            float* __restrict__ out, int n) {
    int tid = threadIdx.x;
    int row = blockIdx.x * 4 + (tid >> 6);
    int lane = tid & 63;
    const float2* xr = (const float2*)(x + (size_t)row * D);
    float2 v = xr[lane];
    __hip_bfloat162 b2;
    b2.x = __float2bfloat16(v.x);
    b2.y = __float2bfloat16(v.y);
    ((__hip_bfloat162*)(xb + (size_t)row * D))[lane] = b2;
    float s = v.x * v.x + v.y * v.y;
    #pragma unroll
    for (int o = 32; o > 0; o >>= 1) s += __shfl_xor(s, o, 64);
    if (lane == 0) {
        sq[row] = s;
        ap[row] = 0u;            // dist >= 0 -> 0 is a valid -inf for max
        an[row] = 0x7F800000u;   // +inf bits
    }
    if (blockIdx.x == 0 && tid == 0) *out = 0.0f;
}

// ---------------- gram: mt=4 (64 i-rows/wave), 16-phase counted-vmcnt ----
// R7: LDS pipe was the tallest floor (each of 16 waves/CU streamed the full
// 128KB B-window => 2MB/CU ~ 10.3us > MFMA 8.3us). mt=2 -> mt=4: each
// ds_read_b128 B-fragment now feeds 4 MFMAs instead of 2, halving per-FLOP
// LDS traffic (floor -> 5.1us); MFMA (8.3us) becomes the dominant pipe.
// Block = 4 waves x 64 i-rows = 256 rows; grid 32x16 = 512 blocks = 2/CU
// (8 waves/CU). VGPR ~160 -> launch_bounds(256,2), no spill.
// Pipeline unchanged: 16 half-tiles of 32 j-rows (8KB), 4-slot LDS ring,
// s_waitcnt vmcnt(4) counted (tiles h+1,h+2 in flight), 1 barrier/phase,
// setprio around the 16-MFMA cluster. Prologue source order (afrag -> li ->
// PREF x3 -> meta -> lgkm wait) preserved: the meta ds_write's implicit
// vmcnt drain guarantees loop-entry vmcnt state, keeping the counted-wait
// hazard-free (verified structure, R6/R7 passed absmax=0).
__launch_bounds__(256, 2)
__global__ void gram_kernel(const __hip_bfloat16* __restrict__ xb,
                            const float* __restrict__ sq,
                            const int* __restrict__ tgt,
                            unsigned* __restrict__ ap,
                            unsigned* __restrict__ an, int n) {
    __shared__ __align__(16) __hip_bfloat16 Bs[4][32 * D];  // 4 x 8KB ring
    __shared__ float sqs[JSPAN];
    __shared__ int   tgs[JSPAN];

    const int tid  = threadIdx.x;
    const int wid  = tid >> 6;
    const int lane = tid & 63;
    const int quad = lane >> 4;
    const int l    = lane & 15;
    const int i0   = blockIdx.x * 256;
    const int j0   = blockIdx.y * JSPAN;
    const int rowbase = i0 + wid * 64;

    // A fragments, register-resident: lane holds A[m=l][k=quad*8+j], 4 m-tiles
    bf16x8 afrag[4][4];
    {
        const __hip_bfloat16* abase = xb + (size_t)(rowbase + l) * D + quad * 8;
        #pragma unroll
        for (int mt = 0; mt < 4; ++mt)
            #pragma unroll
            for (int ks = 0; ks < 4; ++ks)
                afrag[mt][ks] = *(const bf16x8*)(abase + (size_t)mt * 16 * D + ks * 32);
    }

    int li[4][4];
    #pragma unroll
    for (int mt = 0; mt < 4; ++mt)
        #pragma unroll
        for (int reg = 0; reg < 4; ++reg)
            li[mt][reg] = tgt[rowbase + mt * 16 + quad * 4 + reg];

    float lap[16], lan[16];
    #pragma unroll
    for (int k = 0; k < 16; ++k) { lap[k] = -1e30f; lan[k] = 1e30f; }

    // staging: per half-tile (32 rows = 512 chunks of 16B), wave wid owns
    // chunks q = wid*128 + i*64 + lane (2 glds/wave). LDS chunk q holds
    // global (row r=q>>4, chunk c=(q&15)^(r&15)) of the half-tile.
    const char* xbb = (const char*)xb;

    #define PREF_HALF(h)                                                      \
        do {                                                                  \
            const int s_ = (h) & 3;                                           \
            _Pragma("unroll")                                                 \
            for (int i_ = 0; i_ < 2; ++i_) {                                  \
                int q_ = wid * 128 + i_ * 64 + lane;                          \
                int r_ = q_ >> 4;                                             \
                int c_ = (q_ & 15) ^ (r_ & 15);                               \
                const char* g_ = xbb + (size_t)(j0 + (h) * 32 + r_) * 256     \
                                     + (size_t)c_ * 16;                       \
                char* l_ = (char*)Bs + (size_t)s_ * 8192                      \
                         + (size_t)(wid * 128 + i_ * 64) * 16;                \
                __builtin_amdgcn_global_load_lds(                             \
                    (const __attribute__((address_space(1))) void*)g_,        \
                    (__attribute__((address_space(3))) void*)l_, 16, 0, 0);   \
            }                                                                 \
        } while (0)

    // frag read: global row rr=jt*16+l of half, k-chunk kc=ks*4+quad lives
    // at LDS chunk rr*16 + (kc ^ (rr&15)); rr&15 == l.
    #define COMP_HALF(h)                                                      \
        do {                                                                  \
            const char* Bb_ = (const char*)Bs + (size_t)((h) & 3) * 8192;     \
            _Pragma("unroll")                                                 \
            for (int jt = 0; jt < 2; ++jt) {                                  \
                f32x4 acc[4];                                                 \
                _Pragma("unroll")                                             \
                for (int mt = 0; mt < 4; ++mt)                                \
                    acc[mt] = (f32x4){0.f, 0.f, 0.f, 0.f};                    \
                __builtin_amdgcn_s_setprio(1);                                \
                _Pragma("unroll")                                             \
                for (int ks = 0; ks < 4; ++ks) {                              \
                    int q = (jt * 16 + l) * 16 + ((ks * 4 + quad) ^ l);       \
                    bf16x8 bfr = *(const bf16x8*)(Bb_ + (size_t)q * 16);      \
                    _Pragma("unroll")                                         \
                    for (int mt = 0; mt < 4; ++mt)                            \
                        acc[mt] = __builtin_amdgcn_mfma_f32_16x16x32_bf16(    \
                            afrag[mt][ks], bfr, acc[mt], 0, 0, 0);            \
                }                                                             \
                __builtin_amdgcn_s_setprio(0);                                \
                int jb_ = (h) * 32 + jt * 16;                                 \
                float sjc = sqs[jb_ + l];                                     \
                int   tjc = tgs[jb_ + l];                                     \
                _Pragma("unroll")                                             \
                for (int mt = 0; mt < 4; ++mt) {                              \
                    _Pragma("unroll")                                         \
                    for (int reg = 0; reg < 4; ++reg) {                       \
                        float t0 = fmaf(-2.0f, acc[mt][reg], sjc);            \
                        bool s0 = (li[mt][reg] == tjc);                       \
                        lap[mt * 4 + reg] =                                   \
                            fmaxf(lap[mt * 4 + reg], s0 ? t0 : -1e30f);       \
                        lan[mt * 4 + reg] =                                   \
                            fminf(lan[mt * 4 + reg], s0 ? 1e30f : t0);        \
                    }                                                         \
                }                                                             \
            }                                                                 \
        } while (0)

    // prologue: 3 half-tiles in flight + metadata staged
    PREF_HALF(0);
    PREF_HALF(1);
    PREF_HALF(2);
    sqs[tid]       = sq[j0 + tid];
    sqs[tid + 256] = sq[j0 + tid + 256];
    tgs[tid]       = tgt[j0 + tid];
    tgs[tid + 256] = tgt[j0 + tid + 256];
    asm volatile("s_waitcnt lgkmcnt(0)" ::: "memory");

    // steady-state phases: counted vmcnt, one barrier per phase
    for (int h = 0; h < 14; ++h) {
        asm volatile("s_waitcnt vmcnt(4)" ::: "memory");
        __builtin_amdgcn_s_barrier();
        asm volatile("" ::: "memory");       // no load hoisting above barrier
        if (h < 13) PREF_HALF(h + 3);
        COMP_HALF(h);
    }
    // tail phases: drain 2 -> 0
    asm volatile("s_waitcnt vmcnt(2)" ::: "memory");
    __builtin_amdgcn_s_barrier();
    asm volatile("" ::: "memory");
    COMP_HALF(14);
    asm volatile("s_waitcnt vmcnt(0)" ::: "memory");
    __builtin_amdgcn_s_barrier();
    asm volatile("" ::: "memory");
    COMP_HALF(15);

    #undef PREF_HALF
    #undef COMP_HALF

    // reduce across 16 column-lanes (xor<16 stays within quad group)
    #pragma unroll
    for (int mt = 0; mt < 4; ++mt)
        #pragma unroll
        for (int reg = 0; reg < 4; ++reg) {
            float p = lap[mt * 4 + reg], q = lan[mt * 4 + reg];
            #pragma unroll
            for (int o = 1; o < 16; o <<= 1) {
                p = fmaxf(p, __shfl_xor(p, o, 64));
                q = fminf(q, __shfl_xor(q, o, 64));
            }
            if (l == mt * 4 + reg) {   // one writer lane per quad (all 16 lanes)
                int gi = rowbase + mt * 16 + quad * 4 + reg;
                float s = sq[gi];
                atomicMax(&ap[gi], __float_as_uint(fmaxf(s + p, 0.0f)));
                atomicMin(&an[gi], __float_as_uint(fmaxf(s + q, 0.0f)));
            }
        }
}

// ---------------- final: sum relu(ap - an + margin) ----------------
__global__ void final_kernel(const unsigned* __restrict__ ap,
                             const unsigned* __restrict__ an,
                             float* __restrict__ out, int n) {
    int i = blockIdx.x * blockDim.x + threadIdx.x;
    float v = 0.f;
    if (i < n) {
        float p = __uint_as_float(ap[i]);
        float q = __uint_as_float(an[i]);
        v = fmaxf(p - q + MARGIN, 0.0f);
    }
    #pragma unroll
    for (int o = 32; o > 0; o >>= 1) v += __shfl_xor(v, o, 64);
    __shared__ float ws[4];
    int lane = threadIdx.x & 63, w = threadIdx.x >> 6;
    if (lane == 0) ws[w] = v;
    __syncthreads();
    if (threadIdx.x == 0) atomicAdd(out, ws[0] + ws[1] + ws[2] + ws[3]);
}

extern "C" void kernel_launch(void* const* d_in, const int* in_sizes, int n_in,
                              void* d_out, int out_size, void* d_ws, size_t ws_size,
                              hipStream_t stream) {
    const float* x   = (const float*)d_in[0];
    const int*   tgt = (const int*)d_in[1];
    float* out = (float*)d_out;
    const int n = in_sizes[1];              // 8192

    float*          sq = (float*)d_ws;
    unsigned*       ap = (unsigned*)((char*)d_ws + (size_t)n * 4);
    unsigned*       an = ap + n;
    __hip_bfloat16* xb = (__hip_bfloat16*)((char*)d_ws + (size_t)n * 12);

    prep_kernel<<<n / 4, 256, 0, stream>>>(x, sq, ap, an, xb, out, n);
    dim3 grid(n / 256, NSPLIT);
    gram_kernel<<<grid, 256, 0, stream>>>(xb, sq, tgt, ap, an, n);
    final_kernel<<<n / 256, 256, 0, stream>>>(ap, an, out, n);
}